// Round 1
// baseline (1674.909 us; speedup 1.0000x reference)
//
#include <hip/hip_runtime.h>
#include <hip/hip_bf16.h>

#define PDIM 4096
#define PPN ((size_t)PDIM * (size_t)PDIM)

typedef __attribute__((ext_vector_type(8))) short bf16x8;
typedef __attribute__((ext_vector_type(4))) float floatx4;

__device__ __forceinline__ void load_lds16(const __hip_bfloat16* g, void* l) {
  // width-16 global->LDS DMA; LDS dest is wave-uniform base + lane*16
  __builtin_amdgcn_global_load_lds(
      (const __attribute__((address_space(1))) void*)g,
      (__attribute__((address_space(3))) void*)l, 16, 0, 0);
}

// ---- fp32 -> bf16 cast, optional bf16 transpose, optional sum(x^2) ----
__global__ void cast_tr(const float* __restrict__ src,
                        __hip_bfloat16* __restrict__ dstN,
                        __hip_bfloat16* __restrict__ dstT,
                        float* __restrict__ sqAcc) {
  __shared__ float tile[32][33];
  const int bx = blockIdx.x * 32, by = blockIdx.y * 32;
  const int tx = threadIdx.x & 31, ty = threadIdx.x >> 5;  // block = 256
  float lsq = 0.f;
#pragma unroll
  for (int ii = 0; ii < 4; ++ii) {
    const int i = ty + ii * 8;
    const float v = src[(size_t)(by + i) * PDIM + bx + tx];
    tile[i][tx] = v;
    lsq += v * v;
    dstN[(size_t)(by + i) * PDIM + bx + tx] = __float2bfloat16(v);
  }
  if (dstT) {
    __syncthreads();
#pragma unroll
    for (int ii = 0; ii < 4; ++ii) {
      const int i = ty + ii * 8;
      dstT[(size_t)(bx + i) * PDIM + by + tx] = __float2bfloat16(tile[tx][i]);
    }
  }
  if (sqAcc) {
#pragma unroll
    for (int off = 32; off > 0; off >>= 1) lsq += __shfl_down(lsq, off);
    if ((threadIdx.x & 63) == 0) atomicAdd(sqAcc, lsq);
  }
}

// ---- row sums of W_beta -> scale[i] = W^2 / (s*W^2 + 1) ----
__global__ void rowscale(const float* __restrict__ Wb,
                         const float* __restrict__ sAcc,
                         float* __restrict__ scale) {
  const size_t row = blockIdx.x;
  const float* r = Wb + row * PDIM;
  float sum = 0.f;
  for (int j = threadIdx.x; j < PDIM; j += 256) sum += r[j];
#pragma unroll
  for (int off = 32; off > 0; off >>= 1) sum += __shfl_down(sum, off);
  __shared__ float wsum[4];
  if ((threadIdx.x & 63) == 0) wsum[threadIdx.x >> 6] = sum;
  __syncthreads();
  if (threadIdx.x == 0) {
    const float W = wsum[0] + wsum[1] + wsum[2] + wsum[3];
    const float w2 = W * W;
    scale[row] = w2 / ((*sAcc) * w2 + 1.0f);
  }
}

// ---- NT GEMM: C[i,j] = sum_k A[i,k]*B[j,k], 128x128 tile, BK=32 ----
// MODE 0: outF[i,j] = scale[i]*acc ; outB = bf16(same)            (W_matrix)
// MODE 1: outB[i,j] = bf16(acc - sub[i,j])                        (P^T)
// MODE 2: atomicAdd(lossAcc, sum(acc^2))                          (||Z||^2)
template <int MODE>
__global__ __launch_bounds__(256)
void gemm_nt(const __hip_bfloat16* __restrict__ A,
             const __hip_bfloat16* __restrict__ B,
             const float* __restrict__ scale,
             float* __restrict__ outF,
             __hip_bfloat16* __restrict__ outB,
             const __hip_bfloat16* __restrict__ sub,
             float* __restrict__ lossAcc) {
  __shared__ __align__(16) __hip_bfloat16 As[128 * 32];
  __shared__ __align__(16) __hip_bfloat16 Bs[128 * 32];

  const int tid = threadIdx.x;
  const int lane = tid & 63;
  const int wave = tid >> 6;
  const int wm = wave >> 1, wn = wave & 1;

  const size_t rowA0 = (size_t)blockIdx.y * 128;
  const size_t rowB0 = (size_t)blockIdx.x * 128;

  // staging chunks: chunk c covers (row = c>>2, k = (c&3)*8 .. +7), 16B each
  const int c0 = tid, c1 = tid + 256;
  const __hip_bfloat16* gA0 = A + (rowA0 + (size_t)(c0 >> 2)) * PDIM + (c0 & 3) * 8;
  const __hip_bfloat16* gA1 = A + (rowA0 + (size_t)(c1 >> 2)) * PDIM + (c1 & 3) * 8;
  const __hip_bfloat16* gB0 = B + (rowB0 + (size_t)(c0 >> 2)) * PDIM + (c0 & 3) * 8;
  const __hip_bfloat16* gB1 = B + (rowB0 + (size_t)(c1 >> 2)) * PDIM + (c1 & 3) * 8;

  // wave-uniform LDS bases (HW adds lane*16)
  char* ldsA0 = (char*)As + wave * 1024;
  char* ldsA1 = (char*)As + 4096 + wave * 1024;
  char* ldsB0 = (char*)Bs + wave * 1024;
  char* ldsB1 = (char*)Bs + 4096 + wave * 1024;

  floatx4 acc[4][4] = {};

  const int fr = lane & 15;         // A: row-in-16, B: col-in-16
  const int fq = (lane >> 4) * 8;   // k offset within BK

  for (int kt = 0; kt < PDIM; kt += 32) {
    load_lds16(gA0 + kt, ldsA0);
    load_lds16(gA1 + kt, ldsA1);
    load_lds16(gB0 + kt, ldsB0);
    load_lds16(gB1 + kt, ldsB1);
    __syncthreads();

    bf16x8 af[4], bfr[4];
#pragma unroll
    for (int mi = 0; mi < 4; ++mi)
      af[mi] = *(const bf16x8*)&As[(wm * 64 + mi * 16 + fr) * 32 + fq];
#pragma unroll
    for (int ni = 0; ni < 4; ++ni)
      bfr[ni] = *(const bf16x8*)&Bs[(wn * 64 + ni * 16 + fr) * 32 + fq];
#pragma unroll
    for (int mi = 0; mi < 4; ++mi)
#pragma unroll
      for (int ni = 0; ni < 4; ++ni)
        acc[mi][ni] = __builtin_amdgcn_mfma_f32_16x16x32_bf16(
            af[mi], bfr[ni], acc[mi][ni], 0, 0, 0);
    __syncthreads();
  }

  // C/D layout (measured m89/m91): col = lane&15, row = (lane>>4)*4 + reg
  const size_t row0 = rowA0 + wm * 64;
  const size_t col0 = rowB0 + wn * 64;
  const int lr = (lane >> 4) << 2;
  const int lc = lane & 15;

  if constexpr (MODE == 2) {
    float tot = 0.f;
#pragma unroll
    for (int mi = 0; mi < 4; ++mi)
#pragma unroll
      for (int ni = 0; ni < 4; ++ni)
#pragma unroll
        for (int r = 0; r < 4; ++r) tot += acc[mi][ni][r] * acc[mi][ni][r];
#pragma unroll
    for (int off = 32; off > 0; off >>= 1) tot += __shfl_down(tot, off);
    if (lane == 0) atomicAdd(lossAcc, tot);
  } else if constexpr (MODE == 0) {
#pragma unroll
    for (int mi = 0; mi < 4; ++mi) {
#pragma unroll
      for (int r = 0; r < 4; ++r) {
        const size_t row = row0 + mi * 16 + lr + r;
        const float sc = scale[row];
#pragma unroll
        for (int ni = 0; ni < 4; ++ni) {
          const size_t col = col0 + ni * 16 + lc;
          const float v = sc * acc[mi][ni][r];
          outF[row * PDIM + col] = v;
          outB[row * PDIM + col] = __float2bfloat16(v);
        }
      }
    }
  } else {
#pragma unroll
    for (int mi = 0; mi < 4; ++mi) {
#pragma unroll
      for (int r = 0; r < 4; ++r) {
        const size_t row = row0 + mi * 16 + lr + r;
#pragma unroll
        for (int ni = 0; ni < 4; ++ni) {
          const size_t col = col0 + ni * 16 + lc;
          const float v = acc[mi][ni][r] - __bfloat162float(sub[row * PDIM + col]);
          outB[row * PDIM + col] = __float2bfloat16(v);
        }
      }
    }
  }
}

__global__ void finalize(float* __restrict__ out, const float* __restrict__ acc) {
  if (threadIdx.x == 0) out[0] = sqrtf(*acc);
}

extern "C" void kernel_launch(void* const* d_in, const int* in_sizes, int n_in,
                              void* d_out, int out_size, void* d_ws, size_t ws_size,
                              hipStream_t stream) {
  const float* X  = (const float*)d_in[0];  // target
  const float* Y  = (const float*)d_in[1];  // source
  const float* Wb = (const float*)d_in[2];  // W_beta
  float* out = (float*)d_out;               // [0]=loss, [1..]=W_matrix (fp32)

  // workspace layout (~201.3 MB + 16 KB)
  __hip_bfloat16* Xb  = (__hip_bfloat16*)d_ws;  // X bf16          (GEMM1 B)
  __hip_bfloat16* XbT = Xb + PPN;               // X^T bf16        (GEMM2 A)
  __hip_bfloat16* Yb  = XbT + PPN;              // Y bf16          (GEMM1 A)
  __hip_bfloat16* YbT = Yb + PPN;               // Y^T bf16        (GEMM2 epilogue)
  __hip_bfloat16* Wbb = YbT + PPN;              // W_beta bf16     (GEMM3 B)
  __hip_bfloat16* Wmb = Wbb + PPN;              // W_matrix bf16   (GEMM2 B)
  __hip_bfloat16* PTb = Xb;                     // P^T bf16 (aliases Xb; Xb dead after GEMM1)
  float* scale   = (float*)(Wmb + PPN);         // [4096]
  float* sAcc    = scale + PDIM;                // ||X||_F^2 accumulator
  float* lossAcc = sAcc + 1;                    // ||Z||_F^2 accumulator

  hipMemsetAsync(sAcc, 0, 2 * sizeof(float), stream);

  dim3 cgrid(PDIM / 32, PDIM / 32);
  cast_tr<<<cgrid, 256, 0, stream>>>(X, Xb, XbT, sAcc);
  cast_tr<<<cgrid, 256, 0, stream>>>(Y, Yb, YbT, nullptr);
  cast_tr<<<cgrid, 256, 0, stream>>>(Wb, Wbb, nullptr, nullptr);
  rowscale<<<PDIM, 256, 0, stream>>>(Wb, sAcc, scale);

  dim3 ggrid(PDIM / 128, PDIM / 128);
  // GEMM1: Wm[i,j] = scale[i] * sum_k Y[i,k]X[j,k]
  gemm_nt<0><<<ggrid, 256, 0, stream>>>(Yb, Xb, scale, out + 1, Wmb, nullptr, nullptr);
  // GEMM2: PT[b,a] = sum_k XT[b,k]Wm[a,k] - YT[b,a]   (= P[a,b])
  gemm_nt<1><<<ggrid, 256, 0, stream>>>(XbT, Wmb, nullptr, nullptr, PTb, YbT, nullptr);
  // GEMM3: lossAcc += sum over (b,c) of (sum_a PT[b,a]Wb[c,a])^2 = ||W_beta P||_F^2
  gemm_nt<2><<<ggrid, 256, 0, stream>>>(PTb, Wbb, nullptr, nullptr, nullptr, nullptr, lossAcc);

  finalize<<<1, 1, 0, stream>>>(out, lossAcc);
}

// Round 2
// 837.630 us; speedup vs baseline: 1.9996x; 1.9996x over previous
//
#include <hip/hip_runtime.h>
#include <hip/hip_bf16.h>

#define PDIM 4096
#define PPN ((size_t)PDIM * (size_t)PDIM)

typedef __attribute__((ext_vector_type(8))) short bf16x8;
typedef __attribute__((ext_vector_type(4))) float floatx4;

__device__ __forceinline__ void load_lds16(const __hip_bfloat16* g, void* l) {
  __builtin_amdgcn_global_load_lds(
      (const __attribute__((address_space(1))) void*)g,
      (__attribute__((address_space(3))) void*)l, 16, 0, 0);
}

__device__ __forceinline__ unsigned short bf16bits(float f) {
  __hip_bfloat16 h = __float2bfloat16(f);
  return *(unsigned short*)&h;
}

// ---- ||X||_F^2: grid-stride, 1 atomic per block ----
__global__ void sumsq(const float4* __restrict__ x, float* __restrict__ acc) {
  float s = 0.f;
  const size_t n4 = PPN / 4;
  for (size_t i = (size_t)blockIdx.x * 256 + threadIdx.x; i < n4;
       i += (size_t)gridDim.x * 256) {
    const float4 v = x[i];
    s += v.x * v.x + v.y * v.y + v.z * v.z + v.w * v.w;
  }
#pragma unroll
  for (int off = 32; off > 0; off >>= 1) s += __shfl_down(s, off);
  __shared__ float ws[4];
  if ((threadIdx.x & 63) == 0) ws[threadIdx.x >> 6] = s;
  __syncthreads();
  if (threadIdx.x == 0) atomicAdd(acc, ws[0] + ws[1] + ws[2] + ws[3]);
}

// ---- fp32 -> bf16 cast + bf16 transpose, fully vectorized, no atomics ----
__global__ void cast_nt(const float* __restrict__ src,
                        __hip_bfloat16* __restrict__ dstN,
                        __hip_bfloat16* __restrict__ dstT) {
  __shared__ float tile[64][65];  // stride 65: transposed reads are 2-way (free)
  const int bx = blockIdx.x * 64, by = blockIdx.y * 64;
  const int tx = threadIdx.x & 15, ty = threadIdx.x >> 4;
#pragma unroll
  for (int r = 0; r < 4; ++r) {
    const int row = ty + r * 16;
    const float4 v = *(const float4*)&src[(size_t)(by + row) * PDIM + bx + tx * 4];
    tile[row][tx * 4 + 0] = v.x;
    tile[row][tx * 4 + 1] = v.y;
    tile[row][tx * 4 + 2] = v.z;
    tile[row][tx * 4 + 3] = v.w;
    ushort4 o;
    o.x = bf16bits(v.x); o.y = bf16bits(v.y); o.z = bf16bits(v.z); o.w = bf16bits(v.w);
    *(ushort4*)&dstN[(size_t)(by + row) * PDIM + bx + tx * 4] = o;
  }
  __syncthreads();
#pragma unroll
  for (int r = 0; r < 4; ++r) {
    const int i = ty + r * 16;
    ushort4 o;
    o.x = bf16bits(tile[tx * 4 + 0][i]);
    o.y = bf16bits(tile[tx * 4 + 1][i]);
    o.z = bf16bits(tile[tx * 4 + 2][i]);
    o.w = bf16bits(tile[tx * 4 + 3][i]);
    *(ushort4*)&dstT[(size_t)(bx + i) * PDIM + by + tx * 4] = o;
  }
}

// ---- W_beta: cast + row-sum + scale[i] = W^2/(s*W^2+1), one row per block ----
__global__ void cast_wb_rows(const float* __restrict__ Wb,
                             __hip_bfloat16* __restrict__ Wbb,
                             const float* __restrict__ sAcc,
                             float* __restrict__ scale) {
  const size_t row = blockIdx.x;
  const float4* src = (const float4*)(Wb + row * PDIM);
  ushort4* dst = (ushort4*)(Wbb + row * PDIM);
  float sum = 0.f;
#pragma unroll
  for (int it = 0; it < 4; ++it) {
    const int j = threadIdx.x + it * 256;
    const float4 v = src[j];
    sum += (v.x + v.y) + (v.z + v.w);
    ushort4 o;
    o.x = bf16bits(v.x); o.y = bf16bits(v.y); o.z = bf16bits(v.z); o.w = bf16bits(v.w);
    dst[j] = o;
  }
#pragma unroll
  for (int off = 32; off > 0; off >>= 1) sum += __shfl_down(sum, off);
  __shared__ float ws[4];
  if ((threadIdx.x & 63) == 0) ws[threadIdx.x >> 6] = sum;
  __syncthreads();
  if (threadIdx.x == 0) {
    const float W = ws[0] + ws[1] + ws[2] + ws[3];
    const float w2 = W * W;
    scale[row] = w2 / ((*sAcc) * w2 + 1.0f);
  }
}

// ---- NT GEMM: C[i,j] = sum_k A[i,k]*B[j,k], 128x128 tile, BK=32 ----
// MODE 0: outF[i,j] = scale[i]*acc ; outB = bf16(same)            (W_matrix)
// MODE 1: outB[i,j] = bf16(acc - sub[i,j])                        (P^T)
// MODE 2: atomicAdd(lossAcc, sum(acc^2)) — 1 atomic per block     (||Z||^2)
template <int MODE>
__global__ __launch_bounds__(256)
void gemm_nt(const __hip_bfloat16* __restrict__ A,
             const __hip_bfloat16* __restrict__ B,
             const float* __restrict__ scale,
             float* __restrict__ outF,
             __hip_bfloat16* __restrict__ outB,
             const __hip_bfloat16* __restrict__ sub,
             float* __restrict__ lossAcc) {
  __shared__ __align__(16) __hip_bfloat16 As[128 * 32];
  __shared__ __align__(16) __hip_bfloat16 Bs[128 * 32];

  const int tid = threadIdx.x;
  const int lane = tid & 63;
  const int wave = tid >> 6;
  const int wm = wave >> 1, wn = wave & 1;

  const size_t rowA0 = (size_t)blockIdx.y * 128;
  const size_t rowB0 = (size_t)blockIdx.x * 128;

  const int c0 = tid, c1 = tid + 256;
  const __hip_bfloat16* gA0 = A + (rowA0 + (size_t)(c0 >> 2)) * PDIM + (c0 & 3) * 8;
  const __hip_bfloat16* gA1 = A + (rowA0 + (size_t)(c1 >> 2)) * PDIM + (c1 & 3) * 8;
  const __hip_bfloat16* gB0 = B + (rowB0 + (size_t)(c0 >> 2)) * PDIM + (c0 & 3) * 8;
  const __hip_bfloat16* gB1 = B + (rowB0 + (size_t)(c1 >> 2)) * PDIM + (c1 & 3) * 8;

  char* ldsA0 = (char*)As + wave * 1024;
  char* ldsA1 = (char*)As + 4096 + wave * 1024;
  char* ldsB0 = (char*)Bs + wave * 1024;
  char* ldsB1 = (char*)Bs + 4096 + wave * 1024;

  floatx4 acc[4][4] = {};

  const int fr = lane & 15;
  const int fq = (lane >> 4) * 8;

  for (int kt = 0; kt < PDIM; kt += 32) {
    load_lds16(gA0 + kt, ldsA0);
    load_lds16(gA1 + kt, ldsA1);
    load_lds16(gB0 + kt, ldsB0);
    load_lds16(gB1 + kt, ldsB1);
    __syncthreads();

    bf16x8 af[4], bfr[4];
#pragma unroll
    for (int mi = 0; mi < 4; ++mi)
      af[mi] = *(const bf16x8*)&As[(wm * 64 + mi * 16 + fr) * 32 + fq];
#pragma unroll
    for (int ni = 0; ni < 4; ++ni)
      bfr[ni] = *(const bf16x8*)&Bs[(wn * 64 + ni * 16 + fr) * 32 + fq];
#pragma unroll
    for (int mi = 0; mi < 4; ++mi)
#pragma unroll
      for (int ni = 0; ni < 4; ++ni)
        acc[mi][ni] = __builtin_amdgcn_mfma_f32_16x16x32_bf16(
            af[mi], bfr[ni], acc[mi][ni], 0, 0, 0);
    __syncthreads();
  }

  const size_t row0 = rowA0 + wm * 64;
  const size_t col0 = rowB0 + wn * 64;
  const int lr = (lane >> 4) << 2;
  const int lc = lane & 15;

  if constexpr (MODE == 2) {
    float tot = 0.f;
#pragma unroll
    for (int mi = 0; mi < 4; ++mi)
#pragma unroll
      for (int ni = 0; ni < 4; ++ni)
#pragma unroll
        for (int r = 0; r < 4; ++r) tot += acc[mi][ni][r] * acc[mi][ni][r];
#pragma unroll
    for (int off = 32; off > 0; off >>= 1) tot += __shfl_down(tot, off);
    __shared__ float ws[4];
    if (lane == 0) ws[wave] = tot;
    __syncthreads();
    if (tid == 0) atomicAdd(lossAcc, ws[0] + ws[1] + ws[2] + ws[3]);
  } else if constexpr (MODE == 0) {
#pragma unroll
    for (int mi = 0; mi < 4; ++mi) {
#pragma unroll
      for (int r = 0; r < 4; ++r) {
        const size_t row = row0 + mi * 16 + lr + r;
        const float sc = scale[row];
#pragma unroll
        for (int ni = 0; ni < 4; ++ni) {
          const size_t col = col0 + ni * 16 + lc;
          const float v = sc * acc[mi][ni][r];
          outF[row * PDIM + col] = v;
          outB[row * PDIM + col] = __float2bfloat16(v);
        }
      }
    }
  } else {
#pragma unroll
    for (int mi = 0; mi < 4; ++mi) {
#pragma unroll
      for (int r = 0; r < 4; ++r) {
        const size_t row = row0 + mi * 16 + lr + r;
#pragma unroll
        for (int ni = 0; ni < 4; ++ni) {
          const size_t col = col0 + ni * 16 + lc;
          const float v = acc[mi][ni][r] - __bfloat162float(sub[row * PDIM + col]);
          outB[row * PDIM + col] = __float2bfloat16(v);
        }
      }
    }
  }
}

__global__ void finalize(float* __restrict__ out, const float* __restrict__ acc) {
  if (threadIdx.x == 0) out[0] = sqrtf(*acc);
}

extern "C" void kernel_launch(void* const* d_in, const int* in_sizes, int n_in,
                              void* d_out, int out_size, void* d_ws, size_t ws_size,
                              hipStream_t stream) {
  const float* X  = (const float*)d_in[0];  // target
  const float* Y  = (const float*)d_in[1];  // source
  const float* Wb = (const float*)d_in[2];  // W_beta
  float* out = (float*)d_out;               // [0]=loss, [1..]=W_matrix (fp32)

  __hip_bfloat16* Xb  = (__hip_bfloat16*)d_ws;  // X bf16          (GEMM1 B)
  __hip_bfloat16* XbT = Xb + PPN;               // X^T bf16        (GEMM2 A)
  __hip_bfloat16* Yb  = XbT + PPN;              // Y bf16          (GEMM1 A)
  __hip_bfloat16* YbT = Yb + PPN;               // Y^T bf16        (GEMM2 epilogue)
  __hip_bfloat16* Wbb = YbT + PPN;              // W_beta bf16     (GEMM3 B)
  __hip_bfloat16* Wmb = Wbb + PPN;              // W_matrix bf16   (GEMM2 B)
  __hip_bfloat16* PTb = Xb;                     // P^T (aliases Xb; dead after GEMM1)
  float* scale   = (float*)(Wmb + PPN);         // [4096]
  float* sAcc    = scale + PDIM;
  float* lossAcc = sAcc + 1;

  hipMemsetAsync(sAcc, 0, 2 * sizeof(float), stream);

  sumsq<<<1024, 256, 0, stream>>>((const float4*)X, sAcc);

  dim3 cgrid(PDIM / 64, PDIM / 64);
  cast_nt<<<cgrid, 256, 0, stream>>>(X, Xb, XbT);
  cast_nt<<<cgrid, 256, 0, stream>>>(Y, Yb, YbT);
  cast_wb_rows<<<PDIM, 256, 0, stream>>>(Wb, Wbb, sAcc, scale);

  dim3 ggrid(PDIM / 128, PDIM / 128);
  // GEMM1: Wm[i,j] = scale[i] * sum_k Y[i,k]X[j,k]
  gemm_nt<0><<<ggrid, 256, 0, stream>>>(Yb, Xb, scale, out + 1, Wmb, nullptr, nullptr);
  // GEMM2: PT[b,a] = sum_k XT[b,k]Wm[a,k] - YT[b,a]
  gemm_nt<1><<<ggrid, 256, 0, stream>>>(XbT, Wmb, nullptr, nullptr, PTb, YbT, nullptr);
  // GEMM3: lossAcc += ||W_beta P||_F^2
  gemm_nt<2><<<ggrid, 256, 0, stream>>>(PTb, Wbb, nullptr, nullptr, nullptr, nullptr, lossAcc);

  finalize<<<1, 1, 0, stream>>>(out, lossAcc);
}